// Round 4
// baseline (224.173 us; speedup 1.0000x reference)
//
#include <hip/hip_runtime.h>

#define B_ 2
#define S_ 8192
#define H_ 8
#define D_ 64
#define HD_ 512
#define WIN_ 512

typedef __bf16 bf16x8 __attribute__((ext_vector_type(8)));
typedef float f32x4 __attribute__((ext_vector_type(4)));
typedef unsigned short u16;
typedef unsigned int u32;

__device__ __forceinline__ u16 f2bf(float f) {
  u32 u = __float_as_uint(f);
  u += 0x7FFFu + ((u >> 16) & 1u);
  return (u16)(u >> 16);
}

__device__ __forceinline__ bf16x8 cvt8(const float* p) {
  const float4 a = *(const float4*)p;
  const float4 b = *(const float4*)(p + 4);
  union { u16 s[8]; bf16x8 v; } r;
  r.s[0] = f2bf(a.x); r.s[1] = f2bf(a.y); r.s[2] = f2bf(a.z); r.s[3] = f2bf(a.w);
  r.s[4] = f2bf(b.x); r.s[5] = f2bf(b.y); r.s[6] = f2bf(b.z); r.s[7] = f2bf(b.w);
  return r.v;
}

#define MFMA(a, b, c) __builtin_amdgcn_mfma_f32_16x16x32_bf16(a, b, c, 0, 0, 0)

// ---------------------------------------------------------------------------
// V [B,S,H,D] fp32 -> Vt [B,H,D,S] bf16  (LDS-tiled transpose, 64x64 tiles)
// ---------------------------------------------------------------------------
__global__ __launch_bounds__(256) void vtrans_kernel(const float* __restrict__ v,
                                                     u16* __restrict__ vt) {
  const int t = threadIdx.x;
  const int s0 = (blockIdx.x & (S_ / 64 - 1)) * 64;
  const int bh = blockIdx.x >> 7;  // S_/64 = 128
  const int b = bh >> 3, h = bh & 7;
  __shared__ float tile[64][65];
#pragma unroll
  for (int it = 0; it < 16; ++it) {
    int idx = it * 256 + t;
    int r = idx >> 6, c = idx & 63;  // r: s-offset, c: d
    tile[r][c] = v[((size_t)(b * S_ + s0 + r) * H_ + h) * D_ + c];
  }
  __syncthreads();
#pragma unroll
  for (int it = 0; it < 16; ++it) {
    int idx = it * 256 + t;
    int dd = idx >> 6, c = idx & 63;  // dd: d, c: s-offset
    vt[((size_t)(b * H_ + h) * D_ + dd) * S_ + s0 + c] = f2bf(tile[c][dd]);
  }
}

// ---------------------------------------------------------------------------
// generic fp32 -> bf16 conversion (vectorized x4)
// ---------------------------------------------------------------------------
__global__ __launch_bounds__(256) void cvt_kernel(const float* __restrict__ in,
                                                  u16* __restrict__ out, int n4) {
  int i = blockIdx.x * 256 + threadIdx.x;
  if (i < n4) {
    float4 f = ((const float4*)in)[i];
    ushort4 r;
    r.x = f2bf(f.x); r.y = f2bf(f.y); r.z = f2bf(f.z); r.w = f2bf(f.w);
    ((ushort4*)out)[i] = r;
  }
}

// ---------------------------------------------------------------------------
// Sliding-window flash attention.
// One wave per 16-query tile of one (b,h). 4 independent waves per block.
// Q read fp32 (converted in-register), K bf16 [B,S,H,D], V bf16 [B,H,D,S].
// Output: attn [B*S, 512] bf16 (GEMM-ready).
// ---------------------------------------------------------------------------
__global__ __launch_bounds__(256) void attn_kernel(const float* __restrict__ q,
                                                   const u16* __restrict__ kb,
                                                   const u16* __restrict__ vt,
                                                   u16* __restrict__ attn) {
  const int lane = threadIdx.x & 63;
  const int wave = threadIdx.x >> 6;
  const int lg = lane >> 4;      // 0..3
  const int lj = lane & 15;      // 0..15
  const int qc = blockIdx.x & 127;   // S_/64 = 128
  const int bh = blockIdx.x >> 7;
  const int b = bh >> 3, h = bh & 7;
  const int q0 = qc * 64 + wave * 16;

  __shared__ __align__(16) u16 plds[4][16][32];

  // Q fragments (A-layout): row = lj, k(d) = ds*32 + lg*8 + i
  bf16x8 aq0, aq1;
  {
    const float* qrow = q + ((size_t)(b * S_ + q0 + lj) * H_ + h) * D_;
    aq0 = cvt8(qrow + 0 + lg * 8);
    aq1 = cvt8(qrow + 32 + lg * 8);
  }

  f32x4 o0 = {0.f, 0.f, 0.f, 0.f}, o1 = o0, o2 = o0, o3 = o0;
  float m[4], l[4];
#pragma unroll
  for (int r = 0; r < 4; ++r) { m[r] = -1e30f; l[r] = 0.f; }

  int kstart = q0 - (WIN_ - 1);
  if (kstart < 0) kstart = 0;
  kstart &= ~31;

  const float scale = 0.125f;  // 1/sqrt(64)

  for (int kt = kstart; kt < q0 + 16; kt += 32) {
    // ---- QK^T: S[16q x 32k] in two 16-key sub-tiles ----
    const u16* kb0 = kb + ((size_t)(b * S_ + kt + lj) * H_ + h) * D_;        // keys kt..kt+15
    const u16* kb1 = kb + ((size_t)(b * S_ + kt + 16 + lj) * H_ + h) * D_;   // keys kt+16..kt+31
    bf16x8 k00 = *(const bf16x8*)(kb0 + 0 + lg * 8);
    bf16x8 k01 = *(const bf16x8*)(kb0 + 32 + lg * 8);
    bf16x8 k10 = *(const bf16x8*)(kb1 + 0 + lg * 8);
    bf16x8 k11 = *(const bf16x8*)(kb1 + 32 + lg * 8);

    f32x4 sA = {0.f, 0.f, 0.f, 0.f}, sB = sA;
    sA = MFMA(aq0, k00, sA);
    sA = MFMA(aq1, k01, sA);
    sB = MFMA(aq0, k10, sB);
    sB = MFMA(aq1, k11, sB);

    // ---- online softmax over the 32-key tile ----
    float pA[4], pB[4], alpha[4];
#pragma unroll
    for (int r = 0; r < 4; ++r) {
      const int qpos = q0 + lg * 4 + r;
      const int kA = kt + lj, kB = kA + 16;
      const bool okA = (kA <= qpos) && (kA > qpos - WIN_);
      const bool okB = (kB <= qpos) && (kB > qpos - WIN_);
      float sa = okA ? sA[r] * scale : -1e30f;
      float sb = okB ? sB[r] * scale : -1e30f;
      float t = fmaxf(sa, sb);
      t = fmaxf(t, __shfl_xor(t, 1));
      t = fmaxf(t, __shfl_xor(t, 2));
      t = fmaxf(t, __shfl_xor(t, 4));
      t = fmaxf(t, __shfl_xor(t, 8));
      const float mn = fmaxf(m[r], t);
      alpha[r] = __expf(m[r] - mn);
      m[r] = mn;
      float pa = okA ? __expf(sa - mn) : 0.f;
      float pb = okB ? __expf(sb - mn) : 0.f;
      float rs = pa + pb;
      rs += __shfl_xor(rs, 1);
      rs += __shfl_xor(rs, 2);
      rs += __shfl_xor(rs, 4);
      rs += __shfl_xor(rs, 8);
      l[r] = l[r] * alpha[r] + rs;
      pA[r] = pa; pB[r] = pb;
    }

    // ---- P (D-layout) -> A-layout via per-wave LDS roundtrip ----
#pragma unroll
    for (int r = 0; r < 4; ++r) {
      plds[wave][lg * 4 + r][lj] = f2bf(pA[r]);
      plds[wave][lg * 4 + r][16 + lj] = f2bf(pB[r]);
    }
    bf16x8 ap = *(const bf16x8*)&plds[wave][lj][lg * 8];

    // ---- PV: out[16q x 64d] in four 16-col d-groups ----
    const u16* vbase = vt + ((size_t)(b * H_ + h) * D_ + lj) * S_ + kt + lg * 8;
    {
      bf16x8 bv = *(const bf16x8*)(vbase + (size_t)0 * 16 * S_);
      f32x4 t0 = o0;
#pragma unroll
      for (int r = 0; r < 4; ++r) t0[r] *= alpha[r];
      o0 = MFMA(ap, bv, t0);
    }
    {
      bf16x8 bv = *(const bf16x8*)(vbase + (size_t)1 * 16 * S_);
      f32x4 t1 = o1;
#pragma unroll
      for (int r = 0; r < 4; ++r) t1[r] *= alpha[r];
      o1 = MFMA(ap, bv, t1);
    }
    {
      bf16x8 bv = *(const bf16x8*)(vbase + (size_t)2 * 16 * S_);
      f32x4 t2 = o2;
#pragma unroll
      for (int r = 0; r < 4; ++r) t2[r] *= alpha[r];
      o2 = MFMA(ap, bv, t2);
    }
    {
      bf16x8 bv = *(const bf16x8*)(vbase + (size_t)3 * 16 * S_);
      f32x4 t3 = o3;
#pragma unroll
      for (int r = 0; r < 4; ++r) t3[r] *= alpha[r];
      o3 = MFMA(ap, bv, t3);
    }
  }

  // ---- epilogue: normalize and store bf16 [B*S, 512] ----
#pragma unroll
  for (int r = 0; r < 4; ++r) {
    const int row = q0 + lg * 4 + r;
    const float inv = 1.0f / l[r];
    u16* orow = attn + (size_t)(b * S_ + row) * HD_ + h * D_;
    orow[0 * 16 + lj] = f2bf(o0[r] * inv);
    orow[1 * 16 + lj] = f2bf(o1[r] * inv);
    orow[2 * 16 + lj] = f2bf(o2[r] * inv);
    orow[3 * 16 + lj] = f2bf(o3[r] * inv);
  }
}

// ---------------------------------------------------------------------------
// out = attn[16384,512](bf16) @ W[512,512](bf16, row-major, used as B[k][o]=W[o][k])
//       + bias, fp32 out. 32x32 tile per wave, 64x64 per block.
// ---------------------------------------------------------------------------
__global__ __launch_bounds__(256) void gemm_kernel(const u16* __restrict__ A,
                                                   const u16* __restrict__ Wb,
                                                   const float* __restrict__ bias,
                                                   float* __restrict__ out) {
  const int lane = threadIdx.x & 63;
  const int wave = threadIdx.x >> 6;
  const int lg = lane >> 4, lj = lane & 15;
  const int rb = blockIdx.x >> 3;  // 256 row blocks
  const int cb = blockIdx.x & 7;   // 8 col blocks
  const int n0 = rb * 64 + (wave >> 1) * 32;
  const int o0 = cb * 64 + (wave & 1) * 32;

  f32x4 c00 = {0.f, 0.f, 0.f, 0.f}, c01 = c00, c10 = c00, c11 = c00;

  for (int kt = 0; kt < HD_; kt += 32) {
    bf16x8 a0 = *(const bf16x8*)(A + (size_t)(n0 + lj) * HD_ + kt + lg * 8);
    bf16x8 a1 = *(const bf16x8*)(A + (size_t)(n0 + 16 + lj) * HD_ + kt + lg * 8);
    bf16x8 b0 = *(const bf16x8*)(Wb + (size_t)(o0 + lj) * HD_ + kt + lg * 8);
    bf16x8 b1 = *(const bf16x8*)(Wb + (size_t)(o0 + 16 + lj) * HD_ + kt + lg * 8);
    c00 = MFMA(a0, b0, c00);
    c01 = MFMA(a0, b1, c01);
    c10 = MFMA(a1, b0, c10);
    c11 = MFMA(a1, b1, c11);
  }

#pragma unroll
  for (int r = 0; r < 4; ++r) {
    const int r0 = n0 + lg * 4 + r;
    const int r1 = r0 + 16;
    out[(size_t)r0 * HD_ + o0 + lj] = c00[r] + bias[o0 + lj];
    out[(size_t)r0 * HD_ + o0 + 16 + lj] = c01[r] + bias[o0 + 16 + lj];
    out[(size_t)r1 * HD_ + o0 + lj] = c10[r] + bias[o0 + lj];
    out[(size_t)r1 * HD_ + o0 + 16 + lj] = c11[r] + bias[o0 + 16 + lj];
  }
}

// ---------------------------------------------------------------------------
extern "C" void kernel_launch(void* const* d_in, const int* in_sizes, int n_in,
                              void* d_out, int out_size, void* d_ws, size_t ws_size,
                              hipStream_t stream) {
  const float* q = (const float*)d_in[0];
  const float* k = (const float*)d_in[1];
  const float* v = (const float*)d_in[2];
  const float* w = (const float*)d_in[3];
  const float* bias = (const float*)d_in[4];
  float* out = (float*)d_out;

  char* ws = (char*)d_ws;
  u16* vt = (u16*)ws;                        // 16,777,216 B : V^T bf16 [B,H,D,S]
  u16* kbb = (u16*)(ws + 16777216);          // 16,777,216 B : K bf16 [B,S,H,D]
  u16* attn = (u16*)(ws + 33554432);         // 16,777,216 B : attn bf16 [B*S, 512]
  u16* wb = (u16*)(ws + 50331648);           //    524,288 B : W bf16 [512,512]

  // V transpose+convert: B*H*(S/64) = 2048 blocks
  hipLaunchKernelGGL(vtrans_kernel, dim3(2048), dim3(256), 0, stream, v, vt);
  // K convert: 8,388,608 elems / 4 = 2,097,152 threads
  hipLaunchKernelGGL(cvt_kernel, dim3(8192), dim3(256), 0, stream, k, kbb, 2097152);
  // W convert: 262,144 / 4 = 65,536 threads
  hipLaunchKernelGGL(cvt_kernel, dim3(256), dim3(256), 0, stream, w, wb, 65536);
  // attention: B*H*(S/64) = 2048 blocks x 4 waves (16 queries each)
  hipLaunchKernelGGL(attn_kernel, dim3(2048), dim3(256), 0, stream, q, kbb, vt, attn);
  // out-projection GEMM: (16384/64) x (512/64) = 2048 blocks
  hipLaunchKernelGGL(gemm_kernel, dim3(2048), dim3(256), 0, stream, attn, wb, bias, out);
}